// Round 2
// baseline (3583.431 us; speedup 1.0000x reference)
//
#include <hip/hip_runtime.h>

#define N_ATOMS   100000
#define N_BONDS   220000
#define N_MESS    20000
#define N_MSG     (N_MESS + N_BONDS)        // 240000
#define ATOM_FDIM 35
#define BOND_FDIM 5
#define BOND_IN   (ATOM_FDIM + BOND_FDIM)   // 40
#define H         128
#define MAX_NB    10
#define DEPTH     6
#define KO        (ATOM_FDIM + H)           // 163

// bf16 <-> f32 helpers (RNE on store)
static __device__ __forceinline__ float bf2f(unsigned short u) {
    union { unsigned int i; float f; } v; v.i = ((unsigned int)u) << 16; return v.f;
}
static __device__ __forceinline__ unsigned short f2bf(float f) {
    union { float f; unsigned int i; } v; v.f = f;
    unsigned int x = v.i;
    return (unsigned short)((x + 0x7FFFu + ((x >> 16) & 1u)) >> 16);
}

// ---------------------------------------------------------------------------
// tree_conv: convert tree messages fp32 -> bf16 into BOTH msg buffers' prefix.
// ---------------------------------------------------------------------------
__global__ __launch_bounds__(256) void tree_conv(
    const float* __restrict__ tree, ushort* __restrict__ a, ushort* __restrict__ b)
{
    int i = blockIdx.x * 256 + threadIdx.x;      // grid = N_MESS*H/256, exact
    unsigned short v = f2bf(tree[i]);
    a[i] = v; b[i] = v;
}

// ---------------------------------------------------------------------------
// binput0: graph0 = relu(fbonds @ W_i) -> bf16 into msgA graph section.
// 2 bonds per 256-thread block; W_i (40x128 = 20 KB) in LDS.
// ---------------------------------------------------------------------------
__global__ __launch_bounds__(256) void binput0(
    const float* __restrict__ fbonds, const float* __restrict__ Wi,
    ushort* __restrict__ gout)
{
    __shared__ float wi[BOND_IN * H];
    int tid = threadIdx.x;
    for (int i = tid * 4; i < BOND_IN * H; i += 1024)
        *(float4*)&wi[i] = *(const float4*)&Wi[i];
    __syncthreads();

    int j = tid & 127, g = tid >> 7;
    int bond = blockIdx.x * 2 + g;               // grid = 110000, exact
    const float* fb = fbonds + bond * BOND_IN;
    float acc = 0.f;
    #pragma unroll
    for (int k = 0; k < BOND_IN; k++)
        acc += fb[k] * wi[k * H + j];
    gout[bond * H + j] = f2bf(fmaxf(acc, 0.f));
}

// ---------------------------------------------------------------------------
// mp_round: one message-passing round, binput recomputed in-kernel.
//   nei[b]       = sum_n msg_in[bgraph[b][n]]            (bf16 table, branchless)
//   graph_out[b] = relu(fbonds[b]@W_i + nei[b]@W_h)  -> bf16
// 32 bonds / 256-thread block. LDS: w(32K, Wi then Wh halves) + nei(16K) +
// fb(5K) = 53.25 KB -> 3 blocks/CU.
// ---------------------------------------------------------------------------
__global__ __launch_bounds__(256, 3) void mp_round(
    const ushort* __restrict__ msg_in, const float* __restrict__ fbonds,
    const int* __restrict__ bgraph, const float* __restrict__ Wi,
    const float* __restrict__ Wh, ushort* __restrict__ graph_out)
{
    __shared__ float w_lds[64 * H];      // 32 KB
    __shared__ float nei[32 * H];        // 16 KB
    __shared__ float fb[32 * BOND_IN];   // 5 KB

    int tid = threadIdx.x;
    int bond0 = blockIdx.x * 32;         // grid = 6875, exact

    // phase 0: stage fb tile + W_i, gather nei (disjoint LDS, one barrier)
    for (int i = tid * 4; i < 32 * BOND_IN; i += 1024)
        *(float4*)&fb[i] = *(const float4*)&fbonds[bond0 * BOND_IN + i];
    for (int i = tid * 4; i < BOND_IN * H; i += 1024)
        *(float4*)&w_lds[i] = *(const float4*)&Wi[i];
    {
        int j = tid & 127, g = tid >> 7;
        for (int b = g; b < 32; b += 2) {
            const int* bg = bgraph + (bond0 + b) * MAX_NB;
            float acc = 0.f;
            #pragma unroll
            for (int n = 0; n < MAX_NB; n++)
                acc += bf2f(msg_in[bg[n] * H + j]);
            nei[b * H + j] = acc;
        }
    }
    __syncthreads();

    int j4   = (tid & 31) * 4;
    int brow = (tid >> 5) * 4;
    float acc[4][4];
    #pragma unroll
    for (int bb = 0; bb < 4; bb++)
        acc[bb][0] = acc[bb][1] = acc[bb][2] = acc[bb][3] = 0.f;

    // binput = fb @ W_i
    for (int k = 0; k < BOND_IN; k++) {
        float4 w = *(float4*)&w_lds[k * H + j4];
        #pragma unroll
        for (int bb = 0; bb < 4; bb++) {
            float f = fb[(brow + bb) * BOND_IN + k];
            acc[bb][0] += f * w.x; acc[bb][1] += f * w.y;
            acc[bb][2] += f * w.z; acc[bb][3] += f * w.w;
        }
    }

    // + nei @ W_h, W_h staged in two 64-row halves through w_lds
    for (int h = 0; h < 2; h++) {
        __syncthreads();                 // done reading previous w_lds contents
        for (int i = tid * 4; i < 64 * H; i += 1024)
            *(float4*)&w_lds[i] = *(const float4*)&Wh[h * 64 * H + i];
        __syncthreads();
        int kbase = h * 64;
        for (int k = 0; k < 64; k += 4) {
            float4 w0 = *(float4*)&w_lds[(k + 0) * H + j4];
            float4 w1 = *(float4*)&w_lds[(k + 1) * H + j4];
            float4 w2 = *(float4*)&w_lds[(k + 2) * H + j4];
            float4 w3 = *(float4*)&w_lds[(k + 3) * H + j4];
            #pragma unroll
            for (int bb = 0; bb < 4; bb++) {
                float4 nv = *(float4*)&nei[(brow + bb) * H + kbase + k];
                acc[bb][0] += nv.x * w0.x + nv.y * w1.x + nv.z * w2.x + nv.w * w3.x;
                acc[bb][1] += nv.x * w0.y + nv.y * w1.y + nv.z * w2.y + nv.w * w3.y;
                acc[bb][2] += nv.x * w0.z + nv.y * w1.z + nv.z * w2.z + nv.w * w3.z;
                acc[bb][3] += nv.x * w0.w + nv.y * w1.w + nv.z * w2.w + nv.w * w3.w;
            }
        }
    }

    #pragma unroll
    for (int bb = 0; bb < 4; bb++) {
        int bond = bond0 + brow + bb;
        ushort4 o;
        o.x = f2bf(fmaxf(acc[bb][0], 0.f));
        o.y = f2bf(fmaxf(acc[bb][1], 0.f));
        o.z = f2bf(fmaxf(acc[bb][2], 0.f));
        o.w = f2bf(fmaxf(acc[bb][3], 0.f));
        *(ushort4*)&graph_out[bond * H + j4] = o;
    }
}

// ---------------------------------------------------------------------------
// atom_kernel: hidden[a] = relu([fatoms[a], sum_n msg[agraph[a][n]]] @ W_o + b_o)
// 32 atoms / block. LDS: wo half (82x128 = 41984 B) + ain (32x164x4 = 20992 B)
// = 62976 B -> 2 blocks/CU. W_o staged in two k-halves.
// ---------------------------------------------------------------------------
__global__ __launch_bounds__(256, 2) void atom_kernel(
    const float* __restrict__ fatoms, const ushort* __restrict__ msg,
    const int* __restrict__ agraph, const float* __restrict__ Wo,
    const float* __restrict__ bo, float* __restrict__ hidden)
{
    __shared__ float wo[82 * H];
    __shared__ float ain[32 * (KO + 1)];   // row stride 164

    int tid = threadIdx.x;
    int a0 = blockIdx.x * 32;              // grid = 3125, exact

    // phase 0: gather + feature fill + stage W_o rows [0,82)
    {
        int j = tid & 127, g = tid >> 7;
        for (int b = g; b < 32; b += 2) {
            int a = a0 + b;
            const int* ag = agraph + a * MAX_NB;
            float acc = 0.f;
            #pragma unroll
            for (int n = 0; n < MAX_NB; n++)
                acc += bf2f(msg[ag[n] * H + j]);
            ain[b * (KO + 1) + ATOM_FDIM + j] = acc;
            if (j < ATOM_FDIM)
                ain[b * (KO + 1) + j] = fatoms[a * ATOM_FDIM + j];
        }
    }
    for (int i = tid * 4; i < 82 * H; i += 1024)
        *(float4*)&wo[i] = *(const float4*)&Wo[i];
    __syncthreads();

    int j4   = (tid & 31) * 4;
    int brow = (tid >> 5) * 4;
    float4 bo4 = *(const float4*)&bo[j4];
    float acc[4][4];
    #pragma unroll
    for (int bb = 0; bb < 4; bb++) {
        acc[bb][0] = bo4.x; acc[bb][1] = bo4.y; acc[bb][2] = bo4.z; acc[bb][3] = bo4.w;
    }

    for (int k = 0; k < 82; k++) {
        float4 w = *(float4*)&wo[k * H + j4];
        #pragma unroll
        for (int bb = 0; bb < 4; bb++) {
            float av = ain[(brow + bb) * (KO + 1) + k];
            acc[bb][0] += av * w.x; acc[bb][1] += av * w.y;
            acc[bb][2] += av * w.z; acc[bb][3] += av * w.w;
        }
    }
    __syncthreads();
    for (int i = tid * 4; i < 81 * H; i += 1024)
        *(float4*)&wo[i] = *(const float4*)&Wo[82 * H + i];
    __syncthreads();
    for (int k = 0; k < 81; k++) {
        float4 w = *(float4*)&wo[k * H + j4];
        #pragma unroll
        for (int bb = 0; bb < 4; bb++) {
            float av = ain[(brow + bb) * (KO + 1) + 82 + k];
            acc[bb][0] += av * w.x; acc[bb][1] += av * w.y;
            acc[bb][2] += av * w.z; acc[bb][3] += av * w.w;
        }
    }

    #pragma unroll
    for (int bb = 0; bb < 4; bb++) {
        float4 o;
        o.x = fmaxf(acc[bb][0], 0.f);
        o.y = fmaxf(acc[bb][1], 0.f);
        o.z = fmaxf(acc[bb][2], 0.f);
        o.w = fmaxf(acc[bb][3], 0.f);
        *(float4*)&hidden[(a0 + brow + bb) * H + j4] = o;
    }
}

// ---------------------------------------------------------------------------
// pool_kernel: per-molecule mean over sorted mol_ids (binary-searched range).
// ---------------------------------------------------------------------------
__global__ __launch_bounds__(128) void pool_kernel(
    const float* __restrict__ hidden, const int* __restrict__ mol_ids,
    float* __restrict__ out, int n_atoms)
{
    int m = blockIdx.x;
    int j = threadIdx.x;

    int lo = 0, hi = n_atoms;
    while (lo < hi) { int mid = (lo + hi) >> 1; if (mol_ids[mid] < m) lo = mid + 1; else hi = mid; }
    int start = lo;
    hi = n_atoms;
    while (lo < hi) { int mid = (lo + hi) >> 1; if (mol_ids[mid] < m + 1) lo = mid + 1; else hi = mid; }
    int end = lo;

    float acc = 0.f;
    for (int a = start; a < end; a++)
        acc += hidden[a * H + j];
    out[m * H + j] = acc / fmaxf((float)(end - start), 1.f);
}

// ---------------------------------------------------------------------------
extern "C" void kernel_launch(void* const* d_in, const int* in_sizes, int n_in,
                              void* d_out, int out_size, void* d_ws, size_t ws_size,
                              hipStream_t stream)
{
    const float* fatoms  = (const float*)d_in[0];
    const float* fbonds  = (const float*)d_in[1];
    const float* tree    = (const float*)d_in[2];
    const int*   agraph  = (const int*)d_in[3];
    const int*   bgraph  = (const int*)d_in[4];
    const int*   mol_ids = (const int*)d_in[5];
    const float* W_i = (const float*)d_in[7];
    const float* W_h = (const float*)d_in[8];
    const float* W_o = (const float*)d_in[9];
    const float* b_o = (const float*)d_in[10];
    float* out = (float*)d_out;

    // ws: msgA | msgB, each bf16[N_MSG][H] = 61.44 MB (total 122.9 MB).
    // hidden (fp32, 51.2 MB) aliases msgA (dead by atom stage).
    ushort* msgA = (ushort*)d_ws;
    ushort* msgB = msgA + (size_t)N_MSG * H;
    float* hidden = (float*)d_ws;

    tree_conv<<<(N_MESS * H) / 256, 256, 0, stream>>>(tree, msgA, msgB);
    binput0<<<N_BONDS / 2, 256, 0, stream>>>(fbonds, W_i, msgA + (size_t)N_MESS * H);

    const ushort* min = msgA; ushort* mout = msgB;
    for (int r = 0; r < DEPTH - 1; r++) {
        mp_round<<<N_BONDS / 32, 256, 0, stream>>>(min, fbonds, bgraph, W_i, W_h,
                                                   mout + (size_t)N_MESS * H);
        const ushort* t = min; min = mout; mout = (ushort*)t;
    }
    // after 5 rounds the final message table is msgB (== min)

    atom_kernel<<<N_ATOMS / 32, 256, 0, stream>>>(fatoms, min, agraph, W_o, b_o, hidden);

    int n_mols = out_size / H;
    pool_kernel<<<n_mols, 128, 0, stream>>>(hidden, mol_ids, out, N_ATOMS);
}

// Round 3
// 1102.609 us; speedup vs baseline: 3.2500x; 3.2500x over previous
//
#include <hip/hip_runtime.h>

#define N_ATOMS   100000
#define N_BONDS   220000
#define N_MESS    20000
#define N_MSG     (N_MESS + N_BONDS)        // 240000
#define ATOM_FDIM 35
#define BOND_FDIM 5
#define BOND_IN   (ATOM_FDIM + BOND_FDIM)   // 40
#define H         128
#define MAX_NB    10
#define DEPTH     6
#define KO        (ATOM_FDIM + H)           // 163
#define KC        192                       // padded K for [Wi;Wh]: 40+128 -> 192

typedef __attribute__((ext_vector_type(8))) short short8;   // 8 bf16 (4 VGPRs)
typedef __attribute__((ext_vector_type(4))) float f32x4;    // MFMA C/D frag

// bf16 <-> f32 helpers (RNE on store)
static __device__ __forceinline__ float bf2f(unsigned short u) {
    union { unsigned int i; float f; } v; v.i = ((unsigned int)u) << 16; return v.f;
}
static __device__ __forceinline__ unsigned short f2bf(float f) {
    union { float f; unsigned int i; } v; v.f = f;
    unsigned int x = v.i;
    return (unsigned short)((x + 0x7FFFu + ((x >> 16) & 1u)) >> 16);
}

// ---------------------------------------------------------------------------
// tree_conv: fp32 tree messages -> bf16 into BOTH msg buffers' prefix.
// ---------------------------------------------------------------------------
__global__ __launch_bounds__(256) void tree_conv(
    const float* __restrict__ tree, ushort* __restrict__ a, ushort* __restrict__ b)
{
    int i = blockIdx.x * 256 + threadIdx.x;      // grid exact
    unsigned short v = f2bf(tree[i]);
    a[i] = v; b[i] = v;
}

// ---------------------------------------------------------------------------
// wcomb_prep: WcombT[n][k] = bf16 of (k<40 ? Wi[k][n] : k<168 ? Wh[k-40][n] : 0)
// 128 x 192 bf16 = 48 KB, stays L2-resident; B-fragments read it directly.
// ---------------------------------------------------------------------------
__global__ __launch_bounds__(256) void wcomb_prep(
    const float* __restrict__ Wi, const float* __restrict__ Wh,
    ushort* __restrict__ WT)
{
    int i = blockIdx.x * 256 + threadIdx.x;      // grid = 128*192/256 = 96
    int n = i / KC, k = i - n * KC;
    float v = (k < BOND_IN) ? Wi[k * H + n]
            : (k < BOND_IN + H) ? Wh[(k - BOND_IN) * H + n] : 0.f;
    WT[i] = f2bf(v);
}

// ---------------------------------------------------------------------------
// binput0: graph0 = relu(fbonds @ W_i) -> bf16 (initial message). Scalar VALU;
// runs once, not hot.
// ---------------------------------------------------------------------------
__global__ __launch_bounds__(256) void binput0(
    const float* __restrict__ fbonds, const float* __restrict__ Wi,
    ushort* __restrict__ gout)
{
    __shared__ float wi[BOND_IN * H];
    int tid = threadIdx.x;
    for (int i = tid * 4; i < BOND_IN * H; i += 1024)
        *(float4*)&wi[i] = *(const float4*)&Wi[i];
    __syncthreads();

    int j = tid & 127, g = tid >> 7;
    int bond = blockIdx.x * 2 + g;               // grid = 110000, exact
    const float* fb = fbonds + (size_t)bond * BOND_IN;
    float acc = 0.f;
    #pragma unroll
    for (int k = 0; k < BOND_IN; k++)
        acc += fb[k] * wi[k * H + j];
    gout[(size_t)bond * H + j] = f2bf(fmaxf(acc, 0.f));
}

// ---------------------------------------------------------------------------
// mp_round (MFMA): graph_out[b] = relu([fb[b]|nei[b]|0] @ [Wi;Wh;0])
//   X tile (32 x 192 bf16) in LDS, stored as 16-byte "cells":
//   cell(b, k8) = b*25 + k8  (k8 = k>>3; stride 25 breaks bank alignment).
//   A-frag: lane reads X[m=lane&15][k=quad*8..+7]  -> one ds_read_b128/cell.
//   B-frag: lane reads WcombT[n=lane&15][same k]   -> 16B global (L2-hot).
// LDS = 12.8 KB -> occupancy VGPR-bound. 1 barrier per block.
// ---------------------------------------------------------------------------
__global__ __launch_bounds__(256, 4) void mp_round(
    const ushort* __restrict__ msg_in, const float* __restrict__ fbonds,
    const int* __restrict__ bgraph, const ushort* __restrict__ WT,
    ushort* __restrict__ graph_out)
{
    __shared__ ushort Xlds[32 * 25 * 8];   // 800 cells x 16 B = 12800 B

    int tid = threadIdx.x;
    int bond0 = blockIdx.x * 32;           // grid = 6875, exact
    int lane = tid & 63, wv = tid >> 6;

    // --- stage fb part: k in [0,40), coalesced fp32 read, bf16 cvt ---
    for (int i = tid; i < 32 * BOND_IN; i += 256) {
        int b = i / BOND_IN, k = i - b * BOND_IN;
        ushort v = f2bf(fbonds[(size_t)bond0 * BOND_IN + i]);
        Xlds[(b * 25 + (k >> 3)) * 8 + (k & 7)] = v;
    }
    // --- zero pad: k in [168,192) -> cells k8 = 21..23 ---
    if (tid < 96) {
        int b = tid / 3, k8 = 21 + (tid - b * 3);
        *(float4*)&Xlds[(b * 25 + k8) * 8] = float4{0.f, 0.f, 0.f, 0.f};
    }
    // --- gather nei: k in [40,168). wave wv handles rows b = wv, wv+4, ... ;
    //     lane covers msg elements (2*lane, 2*lane+1) of each 256 B row. ---
    for (int b = wv; b < 32; b += 4) {
        const int* bg = bgraph + (size_t)(bond0 + b) * MAX_NB;
        float a0 = 0.f, a1 = 0.f;
        #pragma unroll
        for (int n = 0; n < MAX_NB; n++) {
            int idx = bg[n];
            unsigned int v = *(const unsigned int*)(msg_in + (size_t)idx * H + lane * 2);
            a0 += bf2f((ushort)(v & 0xffffu));
            a1 += bf2f((ushort)(v >> 16));
        }
        int k = BOND_IN + lane * 2;
        unsigned int pack = ((unsigned int)f2bf(a1) << 16) | (unsigned int)f2bf(a0);
        *(unsigned int*)&Xlds[(b * 25 + (k >> 3)) * 8 + (k & 7)] = pack;
    }
    __syncthreads();

    // --- MFMA: wave wv owns output cols [wv*32, wv*32+32) ---
    int n0 = wv * 32;
    int m_lane = lane & 15, quad = lane >> 4;
    f32x4 c00 = {0,0,0,0}, c01 = {0,0,0,0}, c10 = {0,0,0,0}, c11 = {0,0,0,0};

    #pragma unroll
    for (int s = 0; s < KC / 32; s++) {
        short8 a0 = *(const short8*)&Xlds[((m_lane)      * 25 + s * 4 + quad) * 8];
        short8 a1 = *(const short8*)&Xlds[((16 + m_lane) * 25 + s * 4 + quad) * 8];
        short8 b0 = *(const short8*)&WT[(size_t)(n0 + m_lane)      * KC + s * 32 + quad * 8];
        short8 b1 = *(const short8*)&WT[(size_t)(n0 + 16 + m_lane) * KC + s * 32 + quad * 8];
        c00 = __builtin_amdgcn_mfma_f32_16x16x32_bf16(a0, b0, c00, 0, 0, 0);
        c01 = __builtin_amdgcn_mfma_f32_16x16x32_bf16(a0, b1, c01, 0, 0, 0);
        c10 = __builtin_amdgcn_mfma_f32_16x16x32_bf16(a1, b0, c10, 0, 0, 0);
        c11 = __builtin_amdgcn_mfma_f32_16x16x32_bf16(a1, b1, c11, 0, 0, 0);
    }

    // --- epilogue: C layout col=lane&15, row=quad*4+reg (m89-verified) ---
    #pragma unroll
    for (int r = 0; r < 4; r++) {
        int row0 = bond0 + quad * 4 + r;
        int row1 = row0 + 16;
        graph_out[(size_t)row0 * H + n0 + m_lane]      = f2bf(fmaxf(c00[r], 0.f));
        graph_out[(size_t)row0 * H + n0 + 16 + m_lane] = f2bf(fmaxf(c01[r], 0.f));
        graph_out[(size_t)row1 * H + n0 + m_lane]      = f2bf(fmaxf(c10[r], 0.f));
        graph_out[(size_t)row1 * H + n0 + 16 + m_lane] = f2bf(fmaxf(c11[r], 0.f));
    }
}

// ---------------------------------------------------------------------------
// atom_kernel: hidden[a] = relu([fatoms[a], sum_n msg[agraph[a][n]]] @ W_o + b_o)
// (unchanged from round 2 — not the bottleneck yet)
// ---------------------------------------------------------------------------
__global__ __launch_bounds__(256, 2) void atom_kernel(
    const float* __restrict__ fatoms, const ushort* __restrict__ msg,
    const int* __restrict__ agraph, const float* __restrict__ Wo,
    const float* __restrict__ bo, float* __restrict__ hidden)
{
    __shared__ float wo[82 * H];
    __shared__ float ain[32 * (KO + 1)];   // row stride 164

    int tid = threadIdx.x;
    int a0 = blockIdx.x * 32;              // grid = 3125, exact

    {
        int j = tid & 127, g = tid >> 7;
        for (int b = g; b < 32; b += 2) {
            int a = a0 + b;
            const int* ag = agraph + (size_t)a * MAX_NB;
            float acc = 0.f;
            #pragma unroll
            for (int n = 0; n < MAX_NB; n++)
                acc += bf2f(msg[(size_t)ag[n] * H + j]);
            ain[b * (KO + 1) + ATOM_FDIM + j] = acc;
            if (j < ATOM_FDIM)
                ain[b * (KO + 1) + j] = fatoms[(size_t)a * ATOM_FDIM + j];
        }
    }
    for (int i = tid * 4; i < 82 * H; i += 1024)
        *(float4*)&wo[i] = *(const float4*)&Wo[i];
    __syncthreads();

    int j4   = (tid & 31) * 4;
    int brow = (tid >> 5) * 4;
    float4 bo4 = *(const float4*)&bo[j4];
    float acc[4][4];
    #pragma unroll
    for (int bb = 0; bb < 4; bb++) {
        acc[bb][0] = bo4.x; acc[bb][1] = bo4.y; acc[bb][2] = bo4.z; acc[bb][3] = bo4.w;
    }

    for (int k = 0; k < 82; k++) {
        float4 w = *(float4*)&wo[k * H + j4];
        #pragma unroll
        for (int bb = 0; bb < 4; bb++) {
            float av = ain[(brow + bb) * (KO + 1) + k];
            acc[bb][0] += av * w.x; acc[bb][1] += av * w.y;
            acc[bb][2] += av * w.z; acc[bb][3] += av * w.w;
        }
    }
    __syncthreads();
    for (int i = tid * 4; i < 81 * H; i += 1024)
        *(float4*)&wo[i] = *(const float4*)&Wo[82 * H + i];
    __syncthreads();
    for (int k = 0; k < 81; k++) {
        float4 w = *(float4*)&wo[k * H + j4];
        #pragma unroll
        for (int bb = 0; bb < 4; bb++) {
            float av = ain[(brow + bb) * (KO + 1) + 82 + k];
            acc[bb][0] += av * w.x; acc[bb][1] += av * w.y;
            acc[bb][2] += av * w.z; acc[bb][3] += av * w.w;
        }
    }

    #pragma unroll
    for (int bb = 0; bb < 4; bb++) {
        float4 o;
        o.x = fmaxf(acc[bb][0], 0.f);
        o.y = fmaxf(acc[bb][1], 0.f);
        o.z = fmaxf(acc[bb][2], 0.f);
        o.w = fmaxf(acc[bb][3], 0.f);
        *(float4*)&hidden[(size_t)(a0 + brow + bb) * H + j4] = o;
    }
}

// ---------------------------------------------------------------------------
// pool_kernel: per-molecule mean over sorted mol_ids (binary-searched range).
// ---------------------------------------------------------------------------
__global__ __launch_bounds__(128) void pool_kernel(
    const float* __restrict__ hidden, const int* __restrict__ mol_ids,
    float* __restrict__ out, int n_atoms)
{
    int m = blockIdx.x;
    int j = threadIdx.x;

    int lo = 0, hi = n_atoms;
    while (lo < hi) { int mid = (lo + hi) >> 1; if (mol_ids[mid] < m) lo = mid + 1; else hi = mid; }
    int start = lo;
    hi = n_atoms;
    while (lo < hi) { int mid = (lo + hi) >> 1; if (mol_ids[mid] < m + 1) lo = mid + 1; else hi = mid; }
    int end = lo;

    float acc = 0.f;
    for (int a = start; a < end; a++)
        acc += hidden[(size_t)a * H + j];
    out[(size_t)m * H + j] = acc / fmaxf((float)(end - start), 1.f);
}

// ---------------------------------------------------------------------------
extern "C" void kernel_launch(void* const* d_in, const int* in_sizes, int n_in,
                              void* d_out, int out_size, void* d_ws, size_t ws_size,
                              hipStream_t stream)
{
    const float* fatoms  = (const float*)d_in[0];
    const float* fbonds  = (const float*)d_in[1];
    const float* tree    = (const float*)d_in[2];
    const int*   agraph  = (const int*)d_in[3];
    const int*   bgraph  = (const int*)d_in[4];
    const int*   mol_ids = (const int*)d_in[5];
    const float* W_i = (const float*)d_in[7];
    const float* W_h = (const float*)d_in[8];
    const float* W_o = (const float*)d_in[9];
    const float* b_o = (const float*)d_in[10];
    float* out = (float*)d_out;

    // ws: msgA | msgB (bf16[N_MSG][H] each, 61.44 MB) | WcombT (48 KB).
    // hidden (fp32, 51.2 MB) aliases msgA (dead by atom stage).
    ushort* msgA = (ushort*)d_ws;
    ushort* msgB = msgA + (size_t)N_MSG * H;
    ushort* WT   = msgB + (size_t)N_MSG * H;
    float* hidden = (float*)d_ws;

    tree_conv<<<(N_MESS * H) / 256, 256, 0, stream>>>(tree, msgA, msgB);
    wcomb_prep<<<(H * KC) / 256, 256, 0, stream>>>(W_i, W_h, WT);
    binput0<<<N_BONDS / 2, 256, 0, stream>>>(fbonds, W_i, msgA + (size_t)N_MESS * H);

    const ushort* min_ = msgA; ushort* mout = msgB;
    for (int r = 0; r < DEPTH - 1; r++) {
        mp_round<<<N_BONDS / 32, 256, 0, stream>>>(min_, fbonds, bgraph, WT,
                                                   mout + (size_t)N_MESS * H);
        const ushort* t = min_; min_ = mout; mout = (ushort*)t;
    }
    // after 5 rounds the final message table is msgB (== min_)

    atom_kernel<<<N_ATOMS / 32, 256, 0, stream>>>(fatoms, min_, agraph, W_o, b_o, hidden);

    int n_mols = out_size / H;
    pool_kernel<<<n_mols, 128, 0, stream>>>(hidden, mol_ids, out, N_ATOMS);
}

// Round 4
// 888.286 us; speedup vs baseline: 4.0341x; 1.2413x over previous
//
#include <hip/hip_runtime.h>

#define N_ATOMS   100000
#define N_BONDS   220000
#define N_MESS    20000
#define N_MSG     (N_MESS + N_BONDS)        // 240000
#define ATOM_FDIM 35
#define BOND_FDIM 5
#define BOND_IN   (ATOM_FDIM + BOND_FDIM)   // 40
#define H         128
#define MAX_NB    10
#define DEPTH     6
#define KO        (ATOM_FDIM + H)           // 163
#define KC        192                       // padded K for [Wi;Wh]: 40+128 -> 192

typedef __attribute__((ext_vector_type(8))) short short8;   // 8 bf16 (4 VGPRs)
typedef __attribute__((ext_vector_type(4))) float f32x4;    // MFMA C/D frag

// bf16 <-> f32 helpers (RNE on store)
static __device__ __forceinline__ float bf2f(unsigned short u) {
    union { unsigned int i; float f; } v; v.i = ((unsigned int)u) << 16; return v.f;
}
static __device__ __forceinline__ unsigned short f2bf(float f) {
    union { float f; unsigned int i; } v; v.f = f;
    unsigned int x = v.i;
    return (unsigned short)((x + 0x7FFFu + ((x >> 16) & 1u)) >> 16);
}

// ---------------------------------------------------------------------------
// tree_conv: fp32 tree messages -> bf16 into BOTH msg buffers' prefix.
// ---------------------------------------------------------------------------
__global__ __launch_bounds__(256) void tree_conv(
    const float* __restrict__ tree, ushort* __restrict__ a, ushort* __restrict__ b)
{
    int i = blockIdx.x * 256 + threadIdx.x;      // grid exact
    unsigned short v = f2bf(tree[i]);
    a[i] = v; b[i] = v;
}

// ---------------------------------------------------------------------------
// wcomb_prep: WcombT[n][k] = bf16 of (k<40 ? Wi[k][n] : k<168 ? Wh[k-40][n] : 0)
// 128 x 192 bf16 = 48 KB, stays L2-resident; B-fragments read it directly.
// ---------------------------------------------------------------------------
__global__ __launch_bounds__(256) void wcomb_prep(
    const float* __restrict__ Wi, const float* __restrict__ Wh,
    ushort* __restrict__ WT)
{
    int i = blockIdx.x * 256 + threadIdx.x;      // grid = 128*192/256 = 96
    int n = i / KC, k = i - n * KC;
    float v = (k < BOND_IN) ? Wi[k * H + n]
            : (k < BOND_IN + H) ? Wh[(k - BOND_IN) * H + n] : 0.f;
    WT[i] = f2bf(v);
}

// ---------------------------------------------------------------------------
// binput0 (MFMA): graph0 = relu(fbonds @ W_i) -> bf16.
// Same tile structure as mp_round but nei == 0: A-tile k in [40,64) zeroed,
// K-loop cut to 64 (zeros in A nullify the Wh rows living in WT k>=40).
// 32 bonds / block, grid 6875. 8 MFMAs/wave — streaming-bound.
// ---------------------------------------------------------------------------
__global__ __launch_bounds__(256, 4) void binput0(
    const float* __restrict__ fbonds, const ushort* __restrict__ WT,
    ushort* __restrict__ gout)
{
    __shared__ ushort Xlds[32 * 25 * 8];   // reuse mp_round cell layout (only k<64 used)

    int tid = threadIdx.x;
    int bond0 = blockIdx.x * 32;           // grid = 6875, exact
    int lane = tid & 63, wv = tid >> 6;

    // stage fb: k in [0,40)
    for (int i = tid; i < 32 * BOND_IN; i += 256) {
        int b = i / BOND_IN, k = i - b * BOND_IN;
        Xlds[(b * 25 + (k >> 3)) * 8 + (k & 7)] = f2bf(fbonds[(size_t)bond0 * BOND_IN + i]);
    }
    // zero k in [40,64): cells k8 = 5,6,7
    if (tid < 96) {
        int b = tid / 3, k8 = 5 + (tid - b * 3);
        *(float4*)&Xlds[(b * 25 + k8) * 8] = float4{0.f, 0.f, 0.f, 0.f};
    }
    __syncthreads();

    int n0 = wv * 32;
    int m_lane = lane & 15, quad = lane >> 4;
    f32x4 c00 = {0,0,0,0}, c01 = {0,0,0,0}, c10 = {0,0,0,0}, c11 = {0,0,0,0};

    #pragma unroll
    for (int s = 0; s < 2; s++) {          // K = 64 covers fb (k<40) + zeros
        short8 a0 = *(const short8*)&Xlds[((m_lane)      * 25 + s * 4 + quad) * 8];
        short8 a1 = *(const short8*)&Xlds[((16 + m_lane) * 25 + s * 4 + quad) * 8];
        short8 b0 = *(const short8*)&WT[(size_t)(n0 + m_lane)      * KC + s * 32 + quad * 8];
        short8 b1 = *(const short8*)&WT[(size_t)(n0 + 16 + m_lane) * KC + s * 32 + quad * 8];
        c00 = __builtin_amdgcn_mfma_f32_16x16x32_bf16(a0, b0, c00, 0, 0, 0);
        c01 = __builtin_amdgcn_mfma_f32_16x16x32_bf16(a0, b1, c01, 0, 0, 0);
        c10 = __builtin_amdgcn_mfma_f32_16x16x32_bf16(a1, b0, c10, 0, 0, 0);
        c11 = __builtin_amdgcn_mfma_f32_16x16x32_bf16(a1, b1, c11, 0, 0, 0);
    }

    #pragma unroll
    for (int r = 0; r < 4; r++) {
        int row0 = bond0 + quad * 4 + r;
        int row1 = row0 + 16;
        gout[(size_t)row0 * H + n0 + m_lane]      = f2bf(fmaxf(c00[r], 0.f));
        gout[(size_t)row0 * H + n0 + 16 + m_lane] = f2bf(fmaxf(c01[r], 0.f));
        gout[(size_t)row1 * H + n0 + m_lane]      = f2bf(fmaxf(c10[r], 0.f));
        gout[(size_t)row1 * H + n0 + 16 + m_lane] = f2bf(fmaxf(c11[r], 0.f));
    }
}

// ---------------------------------------------------------------------------
// mp_round (MFMA): graph_out[b] = relu([fb[b]|nei[b]|0] @ [Wi;Wh;0])
//   X tile (32 x 192 bf16) in LDS, stored as 16-byte "cells":
//   cell(b, k8) = b*25 + k8  (k8 = k>>3; stride 25 breaks bank alignment).
//   A-frag: lane reads X[m=lane&15][k=quad*8..+7]  -> one ds_read_b128/cell.
//   B-frag: lane reads WcombT[n=lane&15][same k]   -> 16B global (L2-hot).
// LDS = 12.8 KB -> occupancy VGPR-bound. 1 barrier per block.
// ---------------------------------------------------------------------------
__global__ __launch_bounds__(256, 4) void mp_round(
    const ushort* __restrict__ msg_in, const float* __restrict__ fbonds,
    const int* __restrict__ bgraph, const ushort* __restrict__ WT,
    ushort* __restrict__ graph_out)
{
    __shared__ ushort Xlds[32 * 25 * 8];   // 800 cells x 16 B = 12800 B

    int tid = threadIdx.x;
    int bond0 = blockIdx.x * 32;           // grid = 6875, exact
    int lane = tid & 63, wv = tid >> 6;

    // --- stage fb part: k in [0,40), coalesced fp32 read, bf16 cvt ---
    for (int i = tid; i < 32 * BOND_IN; i += 256) {
        int b = i / BOND_IN, k = i - b * BOND_IN;
        ushort v = f2bf(fbonds[(size_t)bond0 * BOND_IN + i]);
        Xlds[(b * 25 + (k >> 3)) * 8 + (k & 7)] = v;
    }
    // --- zero pad: k in [168,192) -> cells k8 = 21..23 ---
    if (tid < 96) {
        int b = tid / 3, k8 = 21 + (tid - b * 3);
        *(float4*)&Xlds[(b * 25 + k8) * 8] = float4{0.f, 0.f, 0.f, 0.f};
    }
    // --- gather nei: k in [40,168). wave wv handles rows b = wv, wv+4, ... ;
    //     lane covers msg elements (2*lane, 2*lane+1) of each 256 B row. ---
    for (int b = wv; b < 32; b += 4) {
        const int* bg = bgraph + (size_t)(bond0 + b) * MAX_NB;
        float a0 = 0.f, a1 = 0.f;
        #pragma unroll
        for (int n = 0; n < MAX_NB; n++) {
            int idx = bg[n];
            unsigned int v = *(const unsigned int*)(msg_in + (size_t)idx * H + lane * 2);
            a0 += bf2f((ushort)(v & 0xffffu));
            a1 += bf2f((ushort)(v >> 16));
        }
        int k = BOND_IN + lane * 2;
        unsigned int pack = ((unsigned int)f2bf(a1) << 16) | (unsigned int)f2bf(a0);
        *(unsigned int*)&Xlds[(b * 25 + (k >> 3)) * 8 + (k & 7)] = pack;
    }
    __syncthreads();

    // --- MFMA: wave wv owns output cols [wv*32, wv*32+32) ---
    int n0 = wv * 32;
    int m_lane = lane & 15, quad = lane >> 4;
    f32x4 c00 = {0,0,0,0}, c01 = {0,0,0,0}, c10 = {0,0,0,0}, c11 = {0,0,0,0};

    #pragma unroll
    for (int s = 0; s < KC / 32; s++) {
        short8 a0 = *(const short8*)&Xlds[((m_lane)      * 25 + s * 4 + quad) * 8];
        short8 a1 = *(const short8*)&Xlds[((16 + m_lane) * 25 + s * 4 + quad) * 8];
        short8 b0 = *(const short8*)&WT[(size_t)(n0 + m_lane)      * KC + s * 32 + quad * 8];
        short8 b1 = *(const short8*)&WT[(size_t)(n0 + 16 + m_lane) * KC + s * 32 + quad * 8];
        c00 = __builtin_amdgcn_mfma_f32_16x16x32_bf16(a0, b0, c00, 0, 0, 0);
        c01 = __builtin_amdgcn_mfma_f32_16x16x32_bf16(a0, b1, c01, 0, 0, 0);
        c10 = __builtin_amdgcn_mfma_f32_16x16x32_bf16(a1, b0, c10, 0, 0, 0);
        c11 = __builtin_amdgcn_mfma_f32_16x16x32_bf16(a1, b1, c11, 0, 0, 0);
    }

    // --- epilogue: C layout col=lane&15, row=quad*4+reg (m89-verified) ---
    #pragma unroll
    for (int r = 0; r < 4; r++) {
        int row0 = bond0 + quad * 4 + r;
        int row1 = row0 + 16;
        graph_out[(size_t)row0 * H + n0 + m_lane]      = f2bf(fmaxf(c00[r], 0.f));
        graph_out[(size_t)row0 * H + n0 + 16 + m_lane] = f2bf(fmaxf(c01[r], 0.f));
        graph_out[(size_t)row1 * H + n0 + m_lane]      = f2bf(fmaxf(c10[r], 0.f));
        graph_out[(size_t)row1 * H + n0 + 16 + m_lane] = f2bf(fmaxf(c11[r], 0.f));
    }
}

// ---------------------------------------------------------------------------
// atom_kernel: hidden[a] = relu([fatoms[a], sum_n msg[agraph[a][n]]] @ W_o + b_o)
// ---------------------------------------------------------------------------
__global__ __launch_bounds__(256, 2) void atom_kernel(
    const float* __restrict__ fatoms, const ushort* __restrict__ msg,
    const int* __restrict__ agraph, const float* __restrict__ Wo,
    const float* __restrict__ bo, float* __restrict__ hidden)
{
    __shared__ float wo[82 * H];
    __shared__ float ain[32 * (KO + 1)];   // row stride 164

    int tid = threadIdx.x;
    int a0 = blockIdx.x * 32;              // grid = 3125, exact

    {
        int j = tid & 127, g = tid >> 7;
        for (int b = g; b < 32; b += 2) {
            int a = a0 + b;
            const int* ag = agraph + (size_t)a * MAX_NB;
            float acc = 0.f;
            #pragma unroll
            for (int n = 0; n < MAX_NB; n++)
                acc += bf2f(msg[(size_t)ag[n] * H + j]);
            ain[b * (KO + 1) + ATOM_FDIM + j] = acc;
            if (j < ATOM_FDIM)
                ain[b * (KO + 1) + j] = fatoms[(size_t)a * ATOM_FDIM + j];
        }
    }
    for (int i = tid * 4; i < 82 * H; i += 1024)
        *(float4*)&wo[i] = *(const float4*)&Wo[i];
    __syncthreads();

    int j4   = (tid & 31) * 4;
    int brow = (tid >> 5) * 4;
    float4 bo4 = *(const float4*)&bo[j4];
    float acc[4][4];
    #pragma unroll
    for (int bb = 0; bb < 4; bb++) {
        acc[bb][0] = bo4.x; acc[bb][1] = bo4.y; acc[bb][2] = bo4.z; acc[bb][3] = bo4.w;
    }

    for (int k = 0; k < 82; k++) {
        float4 w = *(float4*)&wo[k * H + j4];
        #pragma unroll
        for (int bb = 0; bb < 4; bb++) {
            float av = ain[(brow + bb) * (KO + 1) + k];
            acc[bb][0] += av * w.x; acc[bb][1] += av * w.y;
            acc[bb][2] += av * w.z; acc[bb][3] += av * w.w;
        }
    }
    __syncthreads();
    for (int i = tid * 4; i < 81 * H; i += 1024)
        *(float4*)&wo[i] = *(const float4*)&Wo[82 * H + i];
    __syncthreads();
    for (int k = 0; k < 81; k++) {
        float4 w = *(float4*)&wo[k * H + j4];
        #pragma unroll
        for (int bb = 0; bb < 4; bb++) {
            float av = ain[(brow + bb) * (KO + 1) + 82 + k];
            acc[bb][0] += av * w.x; acc[bb][1] += av * w.y;
            acc[bb][2] += av * w.z; acc[bb][3] += av * w.w;
        }
    }

    #pragma unroll
    for (int bb = 0; bb < 4; bb++) {
        float4 o;
        o.x = fmaxf(acc[bb][0], 0.f);
        o.y = fmaxf(acc[bb][1], 0.f);
        o.z = fmaxf(acc[bb][2], 0.f);
        o.w = fmaxf(acc[bb][3], 0.f);
        *(float4*)&hidden[(size_t)(a0 + brow + bb) * H + j4] = o;
    }
}

// ---------------------------------------------------------------------------
// pool_kernel: per-molecule mean over sorted mol_ids (binary-searched range).
// ---------------------------------------------------------------------------
__global__ __launch_bounds__(128) void pool_kernel(
    const float* __restrict__ hidden, const int* __restrict__ mol_ids,
    float* __restrict__ out, int n_atoms)
{
    int m = blockIdx.x;
    int j = threadIdx.x;

    int lo = 0, hi = n_atoms;
    while (lo < hi) { int mid = (lo + hi) >> 1; if (mol_ids[mid] < m) lo = mid + 1; else hi = mid; }
    int start = lo;
    hi = n_atoms;
    while (lo < hi) { int mid = (lo + hi) >> 1; if (mol_ids[mid] < m + 1) lo = mid + 1; else hi = mid; }
    int end = lo;

    float acc = 0.f;
    for (int a = start; a < end; a++)
        acc += hidden[(size_t)a * H + j];
    out[(size_t)m * H + j] = acc / fmaxf((float)(end - start), 1.f);
}

// ---------------------------------------------------------------------------
extern "C" void kernel_launch(void* const* d_in, const int* in_sizes, int n_in,
                              void* d_out, int out_size, void* d_ws, size_t ws_size,
                              hipStream_t stream)
{
    const float* fatoms  = (const float*)d_in[0];
    const float* fbonds  = (const float*)d_in[1];
    const float* tree    = (const float*)d_in[2];
    const int*   agraph  = (const int*)d_in[3];
    const int*   bgraph  = (const int*)d_in[4];
    const int*   mol_ids = (const int*)d_in[5];
    const float* W_i = (const float*)d_in[7];
    const float* W_h = (const float*)d_in[8];
    const float* W_o = (const float*)d_in[9];
    const float* b_o = (const float*)d_in[10];
    float* out = (float*)d_out;

    // ws: msgA | msgB (bf16[N_MSG][H] each, 61.44 MB) | WcombT (48 KB).
    // hidden (fp32, 51.2 MB) aliases msgA (dead by atom stage).
    ushort* msgA = (ushort*)d_ws;
    ushort* msgB = msgA + (size_t)N_MSG * H;
    ushort* WT   = msgB + (size_t)N_MSG * H;
    float* hidden = (float*)d_ws;

    tree_conv<<<(N_MESS * H) / 256, 256, 0, stream>>>(tree, msgA, msgB);
    wcomb_prep<<<(H * KC) / 256, 256, 0, stream>>>(W_i, W_h, WT);
    binput0<<<N_BONDS / 32, 256, 0, stream>>>(fbonds, WT, msgA + (size_t)N_MESS * H);

    const ushort* min_ = msgA; ushort* mout = msgB;
    for (int r = 0; r < DEPTH - 1; r++) {
        mp_round<<<N_BONDS / 32, 256, 0, stream>>>(min_, fbonds, bgraph, WT,
                                                   mout + (size_t)N_MESS * H);
        const ushort* t = min_; min_ = mout; mout = (ushort*)t;
    }
    // after 5 rounds the final message table is msgB (== min_)

    atom_kernel<<<N_ATOMS / 32, 256, 0, stream>>>(fatoms, min_, agraph, W_o, b_o, hidden);

    int n_mols = out_size / H;
    pool_kernel<<<n_mols, 128, 0, stream>>>(hidden, mol_ids, out, N_ATOMS);
}

// Round 5
// 739.015 us; speedup vs baseline: 4.8489x; 1.2020x over previous
//
#include <hip/hip_runtime.h>

#define N_ATOMS   100000
#define N_BONDS   220000
#define N_MESS    20000
#define N_MSG     (N_MESS + N_BONDS)        // 240000
#define ATOM_FDIM 35
#define BOND_FDIM 5
#define BOND_IN   (ATOM_FDIM + BOND_FDIM)   // 40
#define H         128
#define MAX_NB    10
#define DEPTH     6
#define KO        (ATOM_FDIM + H)           // 163
#define KC        192                       // padded K for both GEMMs

typedef __attribute__((ext_vector_type(8))) short short8;   // 8 bf16 (4 VGPRs)
typedef __attribute__((ext_vector_type(4))) float f32x4;    // MFMA C/D frag

// bf16 <-> f32 helpers (RNE on store)
static __device__ __forceinline__ float bf2f(unsigned short u) {
    union { unsigned int i; float f; } v; v.i = ((unsigned int)u) << 16; return v.f;
}
static __device__ __forceinline__ unsigned short f2bf(float f) {
    union { float f; unsigned int i; } v; v.f = f;
    unsigned int x = v.i;
    return (unsigned short)((x + 0x7FFFu + ((x >> 16) & 1u)) >> 16);
}

// ---------------------------------------------------------------------------
// tree_conv: fp32 tree messages -> bf16 into BOTH msg buffers' prefix.
// ---------------------------------------------------------------------------
__global__ __launch_bounds__(256) void tree_conv(
    const float* __restrict__ tree, ushort* __restrict__ a, ushort* __restrict__ b)
{
    int i = blockIdx.x * 256 + threadIdx.x;      // grid exact
    unsigned short v = f2bf(tree[i]);
    a[i] = v; b[i] = v;
}

// ---------------------------------------------------------------------------
// wcomb_prep: WcombT[n][k] = bf16 of (k<40 ? Wi[k][n] : k<168 ? Wh[k-40][n] : 0)
// ---------------------------------------------------------------------------
__global__ __launch_bounds__(256) void wcomb_prep(
    const float* __restrict__ Wi, const float* __restrict__ Wh,
    ushort* __restrict__ WT)
{
    int i = blockIdx.x * 256 + threadIdx.x;      // grid = 128*192/256 = 96
    int n = i / KC, k = i - n * KC;
    float v = (k < BOND_IN) ? Wi[k * H + n]
            : (k < BOND_IN + H) ? Wh[(k - BOND_IN) * H + n] : 0.f;
    WT[i] = f2bf(v);
}

// ---------------------------------------------------------------------------
// wo_prep: K-reordered transposed W_o for the atom stage.
// X layout = [nei(128) | fatoms(35) | 0(29)], so:
//   WoT[n][k] = k<128 ? Wo[(35+k)][n] : k<163 ? Wo[k-128][n] : 0
// ---------------------------------------------------------------------------
__global__ __launch_bounds__(256) void wo_prep(
    const float* __restrict__ Wo, ushort* __restrict__ WoT)
{
    int i = blockIdx.x * 256 + threadIdx.x;      // grid = 128*192/256 = 96
    int n = i / KC, k = i - n * KC;
    float v = (k < H) ? Wo[(ATOM_FDIM + k) * H + n]
            : (k < KO) ? Wo[(k - H) * H + n] : 0.f;
    WoT[i] = f2bf(v);
}

// ---------------------------------------------------------------------------
// binput0 (MFMA): graph0 = relu(fbonds @ W_i) -> bf16. K cut to 64.
// ---------------------------------------------------------------------------
__global__ __launch_bounds__(256, 4) void binput0(
    const float* __restrict__ fbonds, const ushort* __restrict__ WT,
    ushort* __restrict__ gout)
{
    __shared__ ushort Xlds[32 * 25 * 8];

    int tid = threadIdx.x;
    int bond0 = blockIdx.x * 32;           // grid = 6875, exact
    int lane = tid & 63, wv = tid >> 6;

    for (int i = tid; i < 32 * BOND_IN; i += 256) {
        int b = i / BOND_IN, k = i - b * BOND_IN;
        Xlds[(b * 25 + (k >> 3)) * 8 + (k & 7)] = f2bf(fbonds[(size_t)bond0 * BOND_IN + i]);
    }
    if (tid < 96) {
        int b = tid / 3, k8 = 5 + (tid - b * 3);
        *(float4*)&Xlds[(b * 25 + k8) * 8] = float4{0.f, 0.f, 0.f, 0.f};
    }
    __syncthreads();

    int n0 = wv * 32;
    int m_lane = lane & 15, quad = lane >> 4;
    f32x4 c00 = {0,0,0,0}, c01 = {0,0,0,0}, c10 = {0,0,0,0}, c11 = {0,0,0,0};

    #pragma unroll
    for (int s = 0; s < 2; s++) {          // K = 64 covers fb (k<40) + zeros
        short8 a0 = *(const short8*)&Xlds[((m_lane)      * 25 + s * 4 + quad) * 8];
        short8 a1 = *(const short8*)&Xlds[((16 + m_lane) * 25 + s * 4 + quad) * 8];
        short8 b0 = *(const short8*)&WT[(size_t)(n0 + m_lane)      * KC + s * 32 + quad * 8];
        short8 b1 = *(const short8*)&WT[(size_t)(n0 + 16 + m_lane) * KC + s * 32 + quad * 8];
        c00 = __builtin_amdgcn_mfma_f32_16x16x32_bf16(a0, b0, c00, 0, 0, 0);
        c01 = __builtin_amdgcn_mfma_f32_16x16x32_bf16(a0, b1, c01, 0, 0, 0);
        c10 = __builtin_amdgcn_mfma_f32_16x16x32_bf16(a1, b0, c10, 0, 0, 0);
        c11 = __builtin_amdgcn_mfma_f32_16x16x32_bf16(a1, b1, c11, 0, 0, 0);
    }

    #pragma unroll
    for (int r = 0; r < 4; r++) {
        int row0 = bond0 + quad * 4 + r;
        int row1 = row0 + 16;
        gout[(size_t)row0 * H + n0 + m_lane]      = f2bf(fmaxf(c00[r], 0.f));
        gout[(size_t)row0 * H + n0 + 16 + m_lane] = f2bf(fmaxf(c01[r], 0.f));
        gout[(size_t)row1 * H + n0 + m_lane]      = f2bf(fmaxf(c10[r], 0.f));
        gout[(size_t)row1 * H + n0 + 16 + m_lane] = f2bf(fmaxf(c11[r], 0.f));
    }
}

// ---------------------------------------------------------------------------
// mp_round (MFMA): graph_out[b] = relu([fb[b]|nei[b]|0] @ [Wi;Wh;0])
// ---------------------------------------------------------------------------
__global__ __launch_bounds__(256, 4) void mp_round(
    const ushort* __restrict__ msg_in, const float* __restrict__ fbonds,
    const int* __restrict__ bgraph, const ushort* __restrict__ WT,
    ushort* __restrict__ graph_out)
{
    __shared__ ushort Xlds[32 * 25 * 8];   // 800 cells x 16 B = 12800 B

    int tid = threadIdx.x;
    int bond0 = blockIdx.x * 32;           // grid = 6875, exact
    int lane = tid & 63, wv = tid >> 6;

    for (int i = tid; i < 32 * BOND_IN; i += 256) {
        int b = i / BOND_IN, k = i - b * BOND_IN;
        ushort v = f2bf(fbonds[(size_t)bond0 * BOND_IN + i]);
        Xlds[(b * 25 + (k >> 3)) * 8 + (k & 7)] = v;
    }
    if (tid < 96) {
        int b = tid / 3, k8 = 21 + (tid - b * 3);
        *(float4*)&Xlds[(b * 25 + k8) * 8] = float4{0.f, 0.f, 0.f, 0.f};
    }
    for (int b = wv; b < 32; b += 4) {
        const int* bg = bgraph + (size_t)(bond0 + b) * MAX_NB;
        float a0 = 0.f, a1 = 0.f;
        #pragma unroll
        for (int n = 0; n < MAX_NB; n++) {
            int idx = bg[n];
            unsigned int v = *(const unsigned int*)(msg_in + (size_t)idx * H + lane * 2);
            a0 += bf2f((ushort)(v & 0xffffu));
            a1 += bf2f((ushort)(v >> 16));
        }
        int k = BOND_IN + lane * 2;
        unsigned int pack = ((unsigned int)f2bf(a1) << 16) | (unsigned int)f2bf(a0);
        *(unsigned int*)&Xlds[(b * 25 + (k >> 3)) * 8 + (k & 7)] = pack;
    }
    __syncthreads();

    int n0 = wv * 32;
    int m_lane = lane & 15, quad = lane >> 4;
    f32x4 c00 = {0,0,0,0}, c01 = {0,0,0,0}, c10 = {0,0,0,0}, c11 = {0,0,0,0};

    #pragma unroll
    for (int s = 0; s < KC / 32; s++) {
        short8 a0 = *(const short8*)&Xlds[((m_lane)      * 25 + s * 4 + quad) * 8];
        short8 a1 = *(const short8*)&Xlds[((16 + m_lane) * 25 + s * 4 + quad) * 8];
        short8 b0 = *(const short8*)&WT[(size_t)(n0 + m_lane)      * KC + s * 32 + quad * 8];
        short8 b1 = *(const short8*)&WT[(size_t)(n0 + 16 + m_lane) * KC + s * 32 + quad * 8];
        c00 = __builtin_amdgcn_mfma_f32_16x16x32_bf16(a0, b0, c00, 0, 0, 0);
        c01 = __builtin_amdgcn_mfma_f32_16x16x32_bf16(a0, b1, c01, 0, 0, 0);
        c10 = __builtin_amdgcn_mfma_f32_16x16x32_bf16(a1, b0, c10, 0, 0, 0);
        c11 = __builtin_amdgcn_mfma_f32_16x16x32_bf16(a1, b1, c11, 0, 0, 0);
    }

    #pragma unroll
    for (int r = 0; r < 4; r++) {
        int row0 = bond0 + quad * 4 + r;
        int row1 = row0 + 16;
        graph_out[(size_t)row0 * H + n0 + m_lane]      = f2bf(fmaxf(c00[r], 0.f));
        graph_out[(size_t)row0 * H + n0 + 16 + m_lane] = f2bf(fmaxf(c01[r], 0.f));
        graph_out[(size_t)row1 * H + n0 + m_lane]      = f2bf(fmaxf(c10[r], 0.f));
        graph_out[(size_t)row1 * H + n0 + 16 + m_lane] = f2bf(fmaxf(c11[r], 0.f));
    }
}

// ---------------------------------------------------------------------------
// atom_mfma: hidden[a] = relu([nei|fatoms|0] @ WoT^T + b_o)  (fp32 out)
// X layout [nei(128)|fatoms(35)|0(29)] keeps the packed nei writes aligned.
// Bias folded into accumulator init (C cols are bias-uniform).
// ---------------------------------------------------------------------------
__global__ __launch_bounds__(256, 4) void atom_mfma(
    const float* __restrict__ fatoms, const ushort* __restrict__ msg,
    const int* __restrict__ agraph, const ushort* __restrict__ WoT,
    const float* __restrict__ bo, float* __restrict__ hidden)
{
    __shared__ ushort Xlds[32 * 25 * 8];

    int tid = threadIdx.x;
    int a0 = blockIdx.x * 32;              // grid = 3125, exact
    int lane = tid & 63, wv = tid >> 6;

    // fatoms: k in [128,163)
    for (int i = tid; i < 32 * ATOM_FDIM; i += 256) {
        int b = i / ATOM_FDIM, t = i - b * ATOM_FDIM;
        int k = H + t;
        Xlds[(b * 25 + (k >> 3)) * 8 + (k & 7)] = f2bf(fatoms[(size_t)a0 * ATOM_FDIM + i]);
    }
    // zero k in [163,168)
    if (tid < 160) {
        int b = tid / 5, k = 163 + (tid - b * 5);
        Xlds[(b * 25 + (k >> 3)) * 8 + (k & 7)] = 0;
    }
    // zero cells k8 = 21..23 (k in [168,192))
    if (tid < 96) {
        int b = tid / 3, k8 = 21 + (tid - b * 3);
        *(float4*)&Xlds[(b * 25 + k8) * 8] = float4{0.f, 0.f, 0.f, 0.f};
    }
    // gather nei: k in [0,128)
    for (int b = wv; b < 32; b += 4) {
        const int* ag = agraph + (size_t)(a0 + b) * MAX_NB;
        float s0 = 0.f, s1 = 0.f;
        #pragma unroll
        for (int n = 0; n < MAX_NB; n++) {
            int idx = ag[n];
            unsigned int v = *(const unsigned int*)(msg + (size_t)idx * H + lane * 2);
            s0 += bf2f((ushort)(v & 0xffffu));
            s1 += bf2f((ushort)(v >> 16));
        }
        int k = lane * 2;
        unsigned int pack = ((unsigned int)f2bf(s1) << 16) | (unsigned int)f2bf(s0);
        *(unsigned int*)&Xlds[(b * 25 + (k >> 3)) * 8 + (k & 7)] = pack;
    }
    __syncthreads();

    int n0 = wv * 32;
    int m_lane = lane & 15, quad = lane >> 4;
    float bias0 = bo[n0 + m_lane], bias1 = bo[n0 + 16 + m_lane];
    f32x4 c00 = {bias0, bias0, bias0, bias0};
    f32x4 c01 = {bias1, bias1, bias1, bias1};
    f32x4 c10 = {bias0, bias0, bias0, bias0};
    f32x4 c11 = {bias1, bias1, bias1, bias1};

    #pragma unroll
    for (int s = 0; s < KC / 32; s++) {
        short8 a0f = *(const short8*)&Xlds[((m_lane)      * 25 + s * 4 + quad) * 8];
        short8 a1f = *(const short8*)&Xlds[((16 + m_lane) * 25 + s * 4 + quad) * 8];
        short8 b0f = *(const short8*)&WoT[(size_t)(n0 + m_lane)      * KC + s * 32 + quad * 8];
        short8 b1f = *(const short8*)&WoT[(size_t)(n0 + 16 + m_lane) * KC + s * 32 + quad * 8];
        c00 = __builtin_amdgcn_mfma_f32_16x16x32_bf16(a0f, b0f, c00, 0, 0, 0);
        c01 = __builtin_amdgcn_mfma_f32_16x16x32_bf16(a0f, b1f, c01, 0, 0, 0);
        c10 = __builtin_amdgcn_mfma_f32_16x16x32_bf16(a1f, b0f, c10, 0, 0, 0);
        c11 = __builtin_amdgcn_mfma_f32_16x16x32_bf16(a1f, b1f, c11, 0, 0, 0);
    }

    #pragma unroll
    for (int r = 0; r < 4; r++) {
        int row0 = a0 + quad * 4 + r;
        int row1 = row0 + 16;
        hidden[(size_t)row0 * H + n0 + m_lane]      = fmaxf(c00[r], 0.f);
        hidden[(size_t)row0 * H + n0 + 16 + m_lane] = fmaxf(c01[r], 0.f);
        hidden[(size_t)row1 * H + n0 + m_lane]      = fmaxf(c10[r], 0.f);
        hidden[(size_t)row1 * H + n0 + 16 + m_lane] = fmaxf(c11[r], 0.f);
    }
}

// ---------------------------------------------------------------------------
// pool_kernel: per-molecule mean over sorted mol_ids (binary-searched range).
// ---------------------------------------------------------------------------
__global__ __launch_bounds__(128) void pool_kernel(
    const float* __restrict__ hidden, const int* __restrict__ mol_ids,
    float* __restrict__ out, int n_atoms)
{
    int m = blockIdx.x;
    int j = threadIdx.x;

    int lo = 0, hi = n_atoms;
    while (lo < hi) { int mid = (lo + hi) >> 1; if (mol_ids[mid] < m) lo = mid + 1; else hi = mid; }
    int start = lo;
    hi = n_atoms;
    while (lo < hi) { int mid = (lo + hi) >> 1; if (mol_ids[mid] < m + 1) lo = mid + 1; else hi = mid; }
    int end = lo;

    float acc = 0.f;
    for (int a = start; a < end; a++)
        acc += hidden[(size_t)a * H + j];
    out[(size_t)m * H + j] = acc / fmaxf((float)(end - start), 1.f);
}

// ---------------------------------------------------------------------------
extern "C" void kernel_launch(void* const* d_in, const int* in_sizes, int n_in,
                              void* d_out, int out_size, void* d_ws, size_t ws_size,
                              hipStream_t stream)
{
    const float* fatoms  = (const float*)d_in[0];
    const float* fbonds  = (const float*)d_in[1];
    const float* tree    = (const float*)d_in[2];
    const int*   agraph  = (const int*)d_in[3];
    const int*   bgraph  = (const int*)d_in[4];
    const int*   mol_ids = (const int*)d_in[5];
    const float* W_i = (const float*)d_in[7];
    const float* W_h = (const float*)d_in[8];
    const float* W_o = (const float*)d_in[9];
    const float* b_o = (const float*)d_in[10];
    float* out = (float*)d_out;

    // ws: msgA | msgB (bf16, 61.44 MB each) | WT (48 KB) | WoT (48 KB).
    // hidden (fp32, 51.2 MB) aliases msgA (final message lives in msgB).
    ushort* msgA = (ushort*)d_ws;
    ushort* msgB = msgA + (size_t)N_MSG * H;
    ushort* WT   = msgB + (size_t)N_MSG * H;
    ushort* WoT  = WT + (size_t)H * KC;
    float* hidden = (float*)d_ws;

    tree_conv<<<(N_MESS * H) / 256, 256, 0, stream>>>(tree, msgA, msgB);
    wcomb_prep<<<(H * KC) / 256, 256, 0, stream>>>(W_i, W_h, WT);
    wo_prep<<<(H * KC) / 256, 256, 0, stream>>>(W_o, WoT);
    binput0<<<N_BONDS / 32, 256, 0, stream>>>(fbonds, WT, msgA + (size_t)N_MESS * H);

    const ushort* min_ = msgA; ushort* mout = msgB;
    for (int r = 0; r < DEPTH - 1; r++) {
        mp_round<<<N_BONDS / 32, 256, 0, stream>>>(min_, fbonds, bgraph, WT,
                                                   mout + (size_t)N_MESS * H);
        const ushort* t = min_; min_ = mout; mout = (ushort*)t;
    }
    // after 5 rounds the final message table is msgB (== min_)

    atom_mfma<<<N_ATOMS / 32, 256, 0, stream>>>(fatoms, min_, agraph, WoT, b_o, hidden);

    int n_mols = out_size / H;
    pool_kernel<<<n_mols, 128, 0, stream>>>(hidden, mol_ids, out, N_ATOMS);
}